// Round 12
// baseline (224.933 us; speedup 1.0000x reference)
//
#include <hip/hip_runtime.h>

// GAT spatio-temporal model — bf16 MFMA pipeline.
// R12 = R11 base, with attn_heads rewritten as a barrier-free per-wave GEMM:
// P computed lane-exact in A-fragment layout (registers), V B-fragments
// loaded directly from global (m-contiguous), shuffles for row reductions.
// B=8, N=512, Din=64, H=8, F=128, L=2.

constexpr int B = 8, N = 512, DIN = 64, H = 8, F = 128;
constexpr int BN = B * N;          // 4096
constexpr float ALPHA_LR = 0.2f;   // LeakyReLU slope
constexpr float EPS_LN = 1e-5f;
constexpr float FLOW = -3.0e38f;   // "-inf" substitute

typedef __attribute__((ext_vector_type(8))) short short8;  // 8 bf16
typedef __attribute__((ext_vector_type(4))) float f32x4;

__device__ __forceinline__ f32x4 mfma16(short8 a, short8 b, f32x4 c) {
  return __builtin_amdgcn_mfma_f32_16x16x32_bf16(a, b, c, 0, 0, 0);
}

__device__ __forceinline__ short f2bf(float f) {  // RNE f32 -> bf16 bits
  union { float f; unsigned u; } v;
  v.f = f;
  unsigned r = v.u + 0x7FFFu + ((v.u >> 16) & 1u);
  return (short)(r >> 16);
}

// ========== setup: zero sA | adjmask | proj_in | weight transposes ========
// grid 512 x 256  (R11-exact)
__global__ __launch_bounds__(256) void g_setup(
    const float* __restrict__ x, const int* __restrict__ adj,
    const float* __restrict__ Wp, const float* __restrict__ bp,
    const float* __restrict__ W_heads, const float* __restrict__ W_out,
    float* __restrict__ h, short* __restrict__ hb,
    unsigned long long* __restrict__ amask, short* __restrict__ WTh,
    short* __restrict__ WoT, float* __restrict__ sA) {
  __shared__ float T[32][33];
  __shared__ float xr[2][64];
  int bid = blockIdx.x, tid = threadIdx.x;
  for (int i = tid; i < 288; i += 256) sA[(size_t)bid * 288 + i] = 0.f;
  {
    int lane = tid & 63, wv = tid >> 6;
    int v[16];
#pragma unroll
    for (int j = 0; j < 16; j++) {
      int w = (bid + j * 512) * 4 + wv;
      v[j] = adj[(size_t)w * 64 + lane];
    }
#pragma unroll
    for (int j = 0; j < 16; j++) {
      int w = (bid + j * 512) * 4 + wv;
      unsigned long long m = __ballot(v[j] > 0);
      if (lane == 0) amask[w] = m;
    }
  }
  {
    int half = tid >> 7, f = tid & 127;
    int b = bid & 7, v0 = bid >> 3;
    for (int v = v0; v < 256; v += 64) {
      int row = b * 512 + v * 2 + half;
      __syncthreads();
      if (f < 64) xr[half][f] = x[(size_t)row * DIN + f];
      __syncthreads();
      float acc = bp[f];
#pragma unroll
      for (int i = 0; i < DIN; i++)
        acc = fmaf(xr[half][i], Wp[i * F + f], acc);
      acc = fmaxf(acc, 0.f);
      h[(size_t)row * F + f] = acc;
      hb[(size_t)row * F + f] = f2bf(acc);
    }
  }
  {
    const float* in; short* out; int R, C, bx, by, bt;
    if (bid < 256) {
      in = W_heads; out = WTh; R = 128; C = 128;
      bx = bid & 3; by = (bid >> 2) & 3; bt = bid >> 4;
    } else {
      int i = bid - 256;
      in = W_out; out = WoT; R = 1024; C = 128;
      bx = i & 3; by = (i >> 2) & 31; bt = i >> 7;
    }
    int c0 = bx * 32, r0 = by * 32;
    const float* ip = in + (size_t)bt * R * C;
    short* op = out + (size_t)bt * R * C;
    __syncthreads();
    {
      int r = tid >> 3, c4 = (tid & 7) * 4;
      float4 v = *(const float4*)(ip + (size_t)(r0 + r) * C + c0 + c4);
      T[r][c4] = v.x; T[r][c4 + 1] = v.y; T[r][c4 + 2] = v.z; T[r][c4 + 3] = v.w;
    }
    __syncthreads();
    {
      int cr = tid >> 3, q = (tid & 7) * 4;
      short4 o;
      o.x = f2bf(T[q][cr]); o.y = f2bf(T[q + 1][cr]);
      o.z = f2bf(T[q + 2][cr]); o.w = f2bf(T[q + 3][cr]);
      *(short4*)(op + (size_t)(c0 + cr) * R + r0 + q) = o;
    }
  }
}

// ========= head projection: hhT[bh][f_out][n] = WT[h] . hb^T, + s1/s2 =====
// grid 1024 flat (R11-exact, packed-store epilogue)
__global__ __launch_bounds__(256) void k_proj_heads_mfma2(
    const short* __restrict__ WT, const short* __restrict__ hb,
    const float* __restrict__ ah_base, short* __restrict__ hhT,
    float* __restrict__ s1, float* __restrict__ s2) {
  int bid = blockIdx.x;
  int b = bid & 7, hd = (bid >> 3) & 7, ft = (bid >> 6) & 1, nt = bid >> 7;
  int bh = b * 8 + hd;
  int n0 = nt * 64;
  constexpr int LK = 136;
  __shared__ short As[64 * LK];
  __shared__ short Bs[64 * LK];
  int tid = threadIdx.x, lane = tid & 63, w = tid >> 6;
  {
    int r = tid >> 2, q = tid & 3;
    const uint4* g = (const uint4*)(WT + ((size_t)hd * F + ft * 64 + r) * F) + q * 4;
    uint4* lp = (uint4*)(As + r * LK) + q * 4;
    lp[0] = g[0]; lp[1] = g[1]; lp[2] = g[2]; lp[3] = g[3];
  }
  {
    int r = tid >> 2, q = tid & 3;
    const uint4* g = (const uint4*)(hb + ((size_t)(b * N + n0 + r)) * F) + q * 4;
    uint4* lp = (uint4*)(Bs + r * LK) + q * 4;
    lp[0] = g[0]; lp[1] = g[1]; lp[2] = g[2]; lp[3] = g[3];
  }
  __syncthreads();
  int arow = lane & 15, koff = (lane >> 4) * 8;
  f32x4 acc[4] = {};
#pragma unroll
  for (int ks = 0; ks < 4; ks++) {
    short8 bb = *(const short8*)(Bs + (w * 16 + arow) * LK + ks * 32 + koff);
#pragma unroll
    for (int rt = 0; rt < 4; rt++) {
      short8 a = *(const short8*)(As + (rt * 16 + arow) * LK + ks * 32 + koff);
      acc[rt] = mfma16(a, bb, acc[rt]);
    }
  }
  __syncthreads();
  int crow0 = (lane >> 4) * 4;
  {
    int nc = w * 16 + arow;
#pragma unroll
    for (int rt = 0; rt < 4; rt++)
#pragma unroll
      for (int r = 0; r < 4; r++)
        As[(rt * 16 + crow0 + r) * 72 + nc] = f2bf(acc[rt][r]);
  }
  __syncthreads();
  {
    short* outp = hhT + (size_t)bh * F * N + (size_t)(ft * 64) * N + n0;
    int r2 = tid >> 3, e = tid & 7;
#pragma unroll
    for (int rr = 0; rr < 2; rr++) {
      int r = rr * 32 + r2;
      uint4 pv = *(const uint4*)(As + r * 72 + e * 8);
      *(uint4*)(outp + (size_t)r * N + e * 8) = pv;
    }
  }
  const float* ah = ah_base + (size_t)hd * 2 * F;
  float pa1 = 0.f, pa2 = 0.f;
#pragma unroll
  for (int rt = 0; rt < 4; rt++) {
    int fo = ft * 64 + rt * 16 + crow0;
#pragma unroll
    for (int r = 0; r < 4; r++) {
      pa1 = fmaf(ah[fo + r], acc[rt][r], pa1);
      pa2 = fmaf(ah[F + fo + r], acc[rt][r], pa2);
    }
  }
  pa1 += __shfl_xor(pa1, 16); pa1 += __shfl_xor(pa1, 32);
  pa2 += __shfl_xor(pa2, 16); pa2 += __shfl_xor(pa2, 32);
  if (lane < 16) {
    int n = n0 + w * 16 + lane;
    atomicAdd(&s1[(size_t)bh * N + n], pa1);
    atomicAdd(&s2[(size_t)bh * N + n], pa2);
  }
}

// ========= fused attention, 8 heads — barrier-free per-wave GEMM ==========
// grid 512 flat: b = bid&7, hd = (bid>>3)&7, nt = bid>>6 (8 x 64-row tiles).
// Wave w owns rows n0+w*16..+16. Lane computes its own P A-fragment; V
// B-fragments loaded directly from global. Only sync: s2all staging.
__global__ __launch_bounds__(256) void k_attn_heads6(
    const short* __restrict__ VT, const float* __restrict__ s1g,
    const float* __restrict__ s2g, const unsigned long long* __restrict__ amask,
    short* __restrict__ multi) {
  int bid = blockIdx.x;
  int b = bid & 7, hd = (bid >> 3) & 7, nt = bid >> 6;
  int bh = b * 8 + hd;
  int n0 = nt * 64;
  __shared__ float s2all[512];
  int tid = threadIdx.x, lane = tid & 63, w = tid >> 6;
  s2all[tid] = s2g[(size_t)bh * N + tid];
  s2all[tid + 256] = s2g[(size_t)bh * N + tid + 256];
  int r16 = lane & 15, g = lane >> 4;
  int wrow = n0 + w * 16 + r16;  // this lane's Q-row
  const unsigned long long* mp = amask + ((size_t)(b * N + wrow)) * 8;
  float s1v = s1g[(size_t)bh * N + wrow];
  __syncthreads();
  // prepass: masked max of s2 over this lane's 128-col segment, then shfl
  float mx = FLOW;
  {
    unsigned long long m0b = mp[g * 2], m1b = mp[g * 2 + 1];
    int base = g * 128;
    unsigned lo0 = (unsigned)m0b, hi0 = (unsigned)(m0b >> 32);
    unsigned lo1 = (unsigned)m1b, hi1 = (unsigned)(m1b >> 32);
#pragma unroll
    for (int k = 0; k < 32; k++) {
      mx = ((lo0 >> k) & 1u) ? fmaxf(mx, s2all[base + k]) : mx;
      mx = ((hi0 >> k) & 1u) ? fmaxf(mx, s2all[base + 32 + k]) : mx;
      mx = ((lo1 >> k) & 1u) ? fmaxf(mx, s2all[base + 64 + k]) : mx;
      mx = ((hi1 >> k) & 1u) ? fmaxf(mx, s2all[base + 96 + k]) : mx;
    }
  }
  mx = fmaxf(mx, __shfl_xor(mx, 16));
  mx = fmaxf(mx, __shfl_xor(mx, 32));
  float xm = s1v + mx;
  float mr = xm > 0.f ? xm : ALPHA_LR * xm;
  // main loop: 16 chunks of K=32; zero barriers
  const short* Vg = VT + (size_t)bh * F * N;
  float lp = 0.f;
  f32x4 acc[8] = {};
#pragma unroll 2
  for (int mc = 0; mc < 16; mc++) {
    int m0 = mc * 32;
    unsigned bits =
        (unsigned)((mp[mc >> 1] >> (((mc & 1) << 5) + (g << 3))) & 0xffull);
    short8 pa;
#pragma unroll
    for (int j = 0; j < 8; j++) {
      float xv = s1v + s2all[m0 + g * 8 + j];
      xv = xv > 0.f ? xv : ALPHA_LR * xv;
      float pv = __expf(xv - mr);
      pv = ((bits >> j) & 1u) ? pv : 0.f;
      lp += pv;
      pa[j] = f2bf(pv);
    }
#pragma unroll
    for (int ft = 0; ft < 8; ft++) {
      short8 bb =
          *(const short8*)(Vg + ((size_t)(ft * 16 + r16)) * N + m0 + g * 8);
      acc[ft] = mfma16(pa, bb, acc[ft]);
    }
  }
  lp += __shfl_xor(lp, 16);
  lp += __shfl_xor(lp, 32);
  float linv_own = 1.f / lp;  // valid for row r16 (all 4 lane-groups agree)
  // epilogue: C layout col=lane&15 (f within tile), row=(lane>>4)*4+reg
  int crow0 = g * 4;
  float lv[4];
#pragma unroll
  for (int rr = 0; rr < 4; rr++) lv[rr] = __shfl(linv_own, crow0 + rr);
#pragma unroll
  for (int ft = 0; ft < 8; ft++) {
    int fcol = ft * 16 + r16;
#pragma unroll
    for (int rr = 0; rr < 4; rr++) {
      int nrow = n0 + w * 16 + crow0 + rr;
      float v = acc[ft][rr] * lv[rr];
      v = v > 0.f ? v : __expf(v) - 1.f;  // ELU
      multi[((size_t)(b * N + nrow)) * (H * F) + hd * F + fcol] = f2bf(v);
    }
  }
}

// ========= out projection: hsT[b][f_out][n] = WoT . multi^T, + s1/s2 ======
// grid 256 flat (R11-exact, packed-store epilogue)
__global__ __launch_bounds__(256) void k_proj_out_mfma(
    const short* __restrict__ WoT, const short* __restrict__ multi,
    const float* __restrict__ ao, short* __restrict__ hsT,
    float* __restrict__ s1, float* __restrict__ s2) {
  int bid = blockIdx.x;
  int b = bid & 7, ft = (bid >> 3) & 3, nt = bid >> 5;
  constexpr int LK = 136;
  __shared__ short As[32 * LK];
  __shared__ short Bs[64 * LK];
  int tid = threadIdx.x, lane = tid & 63, w = tid >> 6;
  int arow = lane & 15, koff = (lane >> 4) * 8;
  const int KT = H * F;  // 1024
  f32x4 acc[2] = {};
  for (int k0 = 0; k0 < KT; k0 += 128) {
    __syncthreads();
    {
      int r = tid >> 3, e = tid & 7;
      const uint4* gp = (const uint4*)(WoT + (size_t)(ft * 32 + r) * KT + k0) + e * 2;
      uint4* lp = (uint4*)(As + r * LK) + e * 2;
      lp[0] = gp[0]; lp[1] = gp[1];
    }
    {
      int r = tid >> 2, q = tid & 3;
      const uint4* gp =
          (const uint4*)(multi + (size_t)(b * N + nt * 64 + r) * KT + k0) + q * 4;
      uint4* lp = (uint4*)(Bs + r * LK) + q * 4;
      lp[0] = gp[0]; lp[1] = gp[1]; lp[2] = gp[2]; lp[3] = gp[3];
    }
    __syncthreads();
#pragma unroll
    for (int ks = 0; ks < 4; ks++) {
      short8 b0 = *(const short8*)(Bs + (w * 16 + arow) * LK + ks * 32 + koff);
      short8 a0 = *(const short8*)(As + arow * LK + ks * 32 + koff);
      short8 a1 = *(const short8*)(As + (16 + arow) * LK + ks * 32 + koff);
      acc[0] = mfma16(a0, b0, acc[0]);
      acc[1] = mfma16(a1, b0, acc[1]);
    }
  }
  __syncthreads();
  int crow0 = (lane >> 4) * 4;
#pragma unroll
  for (int rt = 0; rt < 2; rt++)
#pragma unroll
    for (int r = 0; r < 4; r++)
      As[(rt * 16 + crow0 + r) * 72 + w * 16 + arow] = f2bf(acc[rt][r]);
  __syncthreads();
  {
    short* op = hsT + (size_t)b * F * N + (size_t)(ft * 32) * N + nt * 64;
    int r = tid >> 3, e = tid & 7;
    uint4 pv = *(const uint4*)(As + r * 72 + e * 8);
    *(uint4*)(op + (size_t)r * N + e * 8) = pv;
  }
  float pa1 = 0.f, pa2 = 0.f;
#pragma unroll
  for (int rt = 0; rt < 2; rt++) {
    int fo = ft * 32 + rt * 16 + crow0;
#pragma unroll
    for (int r = 0; r < 4; r++) {
      pa1 = fmaf(ao[fo + r], acc[rt][r], pa1);
      pa2 = fmaf(ao[F + fo + r], acc[rt][r], pa2);
    }
  }
  pa1 += __shfl_xor(pa1, 16); pa1 += __shfl_xor(pa1, 32);
  pa2 += __shfl_xor(pa2, 16); pa2 += __shfl_xor(pa2, 32);
  if (lane < 16) {
    int n = nt * 64 + w * 16 + lane;
    atomicAdd(&s1[(size_t)b * N + n], pa1);
    atomicAdd(&s2[(size_t)b * N + n], pa2);
  }
}

// ========= fused attention single head + residual + LayerNorm =============
// grid 256 flat (R11-exact)
template <int LAST>
__global__ __launch_bounds__(256) void k_attn_single3(
    const short* __restrict__ VT, const float* __restrict__ s1g,
    const float* __restrict__ s2g, const unsigned long long* __restrict__ amask,
    const float* __restrict__ resid, const float* __restrict__ lng,
    const float* __restrict__ lnb, float* __restrict__ hout,
    short* __restrict__ hbout, float* __restrict__ dout) {
  int bid = blockIdx.x;
  int b = bid & 7, nt = bid >> 3;
  int n0 = nt * 16;
  constexpr int LVK = 136;
  __shared__ short Vs[128 * LVK];
  __shared__ short Pf[4 * 64 * 8];
  __shared__ float s2all[512];
  __shared__ float Ot[16][132];
  __shared__ float redS[16][16], redQ[16][16];
  __shared__ float s1r[16], mrow[16], linv[16], muA[16], rsA[16];

  int tid = threadIdx.x, lane = tid & 63, w = tid >> 6;
  s2all[tid] = s2g[(size_t)b * N + tid];
  s2all[tid + 256] = s2g[(size_t)b * N + tid + 256];
  if (tid < 16) s1r[tid] = s1g[(size_t)b * N + n0 + tid];
  __syncthreads();
  {
    int r = tid & 15, seg = tid >> 4;
    unsigned long long mb = amask[((size_t)(b * N + n0 + r)) * 8 + (seg >> 1)];
    unsigned bits = (unsigned)(mb >> ((seg & 1) * 32));
    float mx = FLOW;
#pragma unroll
    for (int k = 0; k < 32; k++)
      mx = ((bits >> k) & 1u) ? fmaxf(mx, s2all[seg * 32 + k]) : mx;
    redS[r][seg] = mx;
  }
  __syncthreads();
  if (tid < 16) {
    float m2 = FLOW;
#pragma unroll
    for (int k = 0; k < 16; k++) m2 = fmaxf(m2, redS[tid][k]);
    float xm = s1r[tid] + m2;
    mrow[tid] = xm > 0.f ? xm : ALPHA_LR * xm;
  }
  float lp = 0.f;
  int arow = lane & 15, koff = (lane >> 4) * 8;
  int pr = tid & 15, pq = (tid >> 4) & 3;
  f32x4 acc[2] = {};
  const short* Vg = VT + (size_t)b * F * N;
  const unsigned long long* mp = amask + ((size_t)(b * N + n0 + pr)) * 8;
  for (int mc = 0; mc < 4; mc++) {
    int m0 = mc * 128;
    __syncthreads();
    {
      int fr = tid >> 1, hf = tid & 1;
      const uint4* g4 = (const uint4*)(Vg + (size_t)fr * N + m0 + hf * 64);
      uint4* l4 = (uint4*)(Vs + fr * LVK + hf * 64);
#pragma unroll
      for (int k = 0; k < 8; k++) l4[k] = g4[k];
    }
    {
      float s1v = s1r[pr], mr = mrow[pr];
      unsigned bits = (unsigned)(mp[mc * 2 + (w >> 1)] >> ((w & 1) * 32));
      short8 pk;
#pragma unroll
      for (int j = 0; j < 8; j++) {
        float xv = s1v + s2all[m0 + w * 32 + pq * 8 + j];
        xv = xv > 0.f ? xv : ALPHA_LR * xv;
        float p = __expf(xv - mr);
        p = ((bits >> (pq * 8 + j)) & 1u) ? p : 0.f;
        lp += p;
        pk[j] = f2bf(p);
      }
      *(short8*)(Pf + (w * 64 + ((pq << 4) | pr)) * 8) = pk;
    }
    __syncthreads();
#pragma unroll
    for (int ks = 0; ks < 4; ks++) {
      short8 a = *(const short8*)(Pf + (ks * 64 + lane) * 8);
#pragma unroll
      for (int cj = 0; cj < 2; cj++) {
        short8 bb = *(const short8*)(Vs + ((w * 2 + cj) * 16 + arow) * LVK +
                                     ks * 32 + koff);
        acc[cj] = mfma16(a, bb, acc[cj]);
      }
    }
  }
  __syncthreads();
  redS[pr][tid >> 4] = lp;
  __syncthreads();
  if (tid < 16) {
    float l = 0.f;
#pragma unroll
    for (int k = 0; k < 16; k++) l += redS[tid][k];
    linv[tid] = 1.f / l;
  }
  __syncthreads();
  int crow0 = (lane >> 4) * 4;
#pragma unroll
  for (int cj = 0; cj < 2; cj++) {
    int fcol = (w * 2 + cj) * 16 + arow;
#pragma unroll
    for (int rr = 0; rr < 4; rr++) {
      int row = crow0 + rr;
      Ot[row][fcol] = acc[cj][rr] * linv[row];
    }
  }
  __syncthreads();
  int r2 = tid >> 4, f8 = (tid & 15) * 8;
  size_t gbase = ((size_t)(b * N + n0 + r2)) * F + f8;
  float v[8];
  float s = 0.f, sq = 0.f;
#pragma unroll
  for (int j = 0; j < 8; j++) {
    float t = Ot[r2][f8 + j] + resid[gbase + j];
    v[j] = t;
    s += t;
    sq = fmaf(t, t, sq);
  }
  redS[r2][tid & 15] = s;
  redQ[r2][tid & 15] = sq;
  __syncthreads();
  if (tid < 16) {
    float ss = 0.f, qq = 0.f;
#pragma unroll
    for (int k = 0; k < 16; k++) { ss += redS[tid][k]; qq += redQ[tid][k]; }
    float mu = ss * (1.f / F);
    muA[tid] = mu;
    rsA[tid] = rsqrtf(qq * (1.f / F) - mu * mu + EPS_LN);
  }
  __syncthreads();
  float mu = muA[r2], rs = rsA[r2];
#pragma unroll
  for (int j = 0; j < 8; j++) {
    float y = (v[j] - mu) * rs * lng[f8 + j] + lnb[f8 + j];
    if (LAST) {
      dout[gbase + j] = y;
    } else {
      y = fmaxf(y, 0.f);
      hout[gbase + j] = y;
      hbout[gbase + j] = f2bf(y);
    }
  }
}

extern "C" void kernel_launch(void* const* d_in, const int* in_sizes, int n_in,
                              void* d_out, int out_size, void* d_ws,
                              size_t ws_size, hipStream_t stream) {
  const float* x = (const float*)d_in[0];
  const int* adj = (const int*)d_in[1];
  const float* Wp = (const float*)d_in[2];
  const float* bp = (const float*)d_in[3];
  const float* W_heads = (const float*)d_in[4];
  const float* a_heads = (const float*)d_in[5];
  const float* W_out = (const float*)d_in[6];
  const float* a_out = (const float*)d_in[7];
  const float* ln_g = (const float*)d_in[8];
  const float* ln_b = (const float*)d_in[9];

  char* p = (char*)d_ws;
  auto alloc = [&](size_t bytes) {
    char* r = p;
    p += (bytes + 255) & ~(size_t)255;
    return r;
  };
  float* sA = (float*)alloc((size_t)2 * 73728 * 4);
  short* WTh = (short*)alloc((size_t)2 * H * F * F * 2);
  short* WoT = (short*)alloc((size_t)2 * H * F * F * 2);
  unsigned long long* amask = (unsigned long long*)alloc((size_t)BN * 8 * 8);
  float* h = (float*)alloc((size_t)BN * F * 4);
  short* hb = (short*)alloc((size_t)BN * F * 2);
  short* hhT = (short*)alloc((size_t)B * H * F * N * 2);
  short* multi = (short*)alloc((size_t)BN * H * F * 2);
  short* hsT = (short*)alloc((size_t)B * F * N * 2);

  g_setup<<<512, 256, 0, stream>>>(x, adj, Wp, bp, W_heads, W_out, h, hb,
                                   amask, WTh, WoT, sA);
  for (int l = 0; l < 2; l++) {
    float* s1h = sA + (size_t)l * 73728;
    float* s2h = s1h + 32768;
    float* s1o = s2h + 32768;
    float* s2o = s1o + 4096;
    k_proj_heads_mfma2<<<dim3(1024), 256, 0, stream>>>(
        WTh + (size_t)l * H * F * F, hb, a_heads + (size_t)l * H * 2 * F, hhT,
        s1h, s2h);
    k_attn_heads6<<<dim3(512), 256, 0, stream>>>(hhT, s1h, s2h, amask, multi);
    k_proj_out_mfma<<<dim3(256), 256, 0, stream>>>(
        WoT + (size_t)l * F * H * F, multi, a_out + (size_t)l * 2 * F, hsT, s1o,
        s2o);
    if (l == 0)
      k_attn_single3<0><<<dim3(256), 256, 0, stream>>>(
          hsT, s1o, s2o, amask, h, ln_g, ln_b, h, hb, nullptr);
    else
      k_attn_single3<1><<<dim3(256), 256, 0, stream>>>(
          hsT, s1o, s2o, amask, h, ln_g + F, ln_b + F, nullptr, nullptr,
          (float*)d_out);
  }
}

// Round 13
// 169.001 us; speedup vs baseline: 1.3310x; 1.3310x over previous
//
#include <hip/hip_runtime.h>

// GAT spatio-temporal model — bf16 MFMA pipeline.
// R13 = R11 base + block-wide unmasked s2-max (softmax shift-invariance)
// replacing the per-row masked-max prepass in both attention kernels, and
// cheaper bf16 rounding. R12's barrier-free attention reverted.
// B=8, N=512, Din=64, H=8, F=128, L=2.

constexpr int B = 8, N = 512, DIN = 64, H = 8, F = 128;
constexpr int BN = B * N;          // 4096
constexpr float ALPHA_LR = 0.2f;   // LeakyReLU slope
constexpr float EPS_LN = 1e-5f;

typedef __attribute__((ext_vector_type(8))) short short8;  // 8 bf16
typedef __attribute__((ext_vector_type(4))) float f32x4;

__device__ __forceinline__ f32x4 mfma16(short8 a, short8 b, f32x4 c) {
  return __builtin_amdgcn_mfma_f32_16x16x32_bf16(a, b, c, 0, 0, 0);
}

__device__ __forceinline__ short f2bf(float f) {  // RN (ties up) f32 -> bf16
  union { float f; unsigned u; } v;
  v.f = f;
  return (short)((v.u + 0x8000u) >> 16);
}

// ========== setup: zero sA | adjmask | proj_in | weight transposes ========
// grid 512 x 256  (R11-exact)
__global__ __launch_bounds__(256) void g_setup(
    const float* __restrict__ x, const int* __restrict__ adj,
    const float* __restrict__ Wp, const float* __restrict__ bp,
    const float* __restrict__ W_heads, const float* __restrict__ W_out,
    float* __restrict__ h, short* __restrict__ hb,
    unsigned long long* __restrict__ amask, short* __restrict__ WTh,
    short* __restrict__ WoT, float* __restrict__ sA) {
  __shared__ float T[32][33];
  __shared__ float xr[2][64];
  int bid = blockIdx.x, tid = threadIdx.x;
  for (int i = tid; i < 288; i += 256) sA[(size_t)bid * 288 + i] = 0.f;
  {
    int lane = tid & 63, wv = tid >> 6;
    int v[16];
#pragma unroll
    for (int j = 0; j < 16; j++) {
      int w = (bid + j * 512) * 4 + wv;
      v[j] = adj[(size_t)w * 64 + lane];
    }
#pragma unroll
    for (int j = 0; j < 16; j++) {
      int w = (bid + j * 512) * 4 + wv;
      unsigned long long m = __ballot(v[j] > 0);
      if (lane == 0) amask[w] = m;
    }
  }
  {
    int half = tid >> 7, f = tid & 127;
    int b = bid & 7, v0 = bid >> 3;
    for (int v = v0; v < 256; v += 64) {
      int row = b * 512 + v * 2 + half;
      __syncthreads();
      if (f < 64) xr[half][f] = x[(size_t)row * DIN + f];
      __syncthreads();
      float acc = bp[f];
#pragma unroll
      for (int i = 0; i < DIN; i++)
        acc = fmaf(xr[half][i], Wp[i * F + f], acc);
      acc = fmaxf(acc, 0.f);
      h[(size_t)row * F + f] = acc;
      hb[(size_t)row * F + f] = f2bf(acc);
    }
  }
  {
    const float* in; short* out; int R, C, bx, by, bt;
    if (bid < 256) {
      in = W_heads; out = WTh; R = 128; C = 128;
      bx = bid & 3; by = (bid >> 2) & 3; bt = bid >> 4;
    } else {
      int i = bid - 256;
      in = W_out; out = WoT; R = 1024; C = 128;
      bx = i & 3; by = (i >> 2) & 31; bt = i >> 7;
    }
    int c0 = bx * 32, r0 = by * 32;
    const float* ip = in + (size_t)bt * R * C;
    short* op = out + (size_t)bt * R * C;
    __syncthreads();
    {
      int r = tid >> 3, c4 = (tid & 7) * 4;
      float4 v = *(const float4*)(ip + (size_t)(r0 + r) * C + c0 + c4);
      T[r][c4] = v.x; T[r][c4 + 1] = v.y; T[r][c4 + 2] = v.z; T[r][c4 + 3] = v.w;
    }
    __syncthreads();
    {
      int cr = tid >> 3, q = (tid & 7) * 4;
      short4 o;
      o.x = f2bf(T[q][cr]); o.y = f2bf(T[q + 1][cr]);
      o.z = f2bf(T[q + 2][cr]); o.w = f2bf(T[q + 3][cr]);
      *(short4*)(op + (size_t)(c0 + cr) * R + r0 + q) = o;
    }
  }
}

// ========= head projection: hhT[bh][f_out][n] = WT[h] . hb^T, + s1/s2 =====
// grid 1024 flat (R11-exact, packed-store epilogue)
__global__ __launch_bounds__(256) void k_proj_heads_mfma2(
    const short* __restrict__ WT, const short* __restrict__ hb,
    const float* __restrict__ ah_base, short* __restrict__ hhT,
    float* __restrict__ s1, float* __restrict__ s2) {
  int bid = blockIdx.x;
  int b = bid & 7, hd = (bid >> 3) & 7, ft = (bid >> 6) & 1, nt = bid >> 7;
  int bh = b * 8 + hd;
  int n0 = nt * 64;
  constexpr int LK = 136;
  __shared__ short As[64 * LK];
  __shared__ short Bs[64 * LK];
  int tid = threadIdx.x, lane = tid & 63, w = tid >> 6;
  {
    int r = tid >> 2, q = tid & 3;
    const uint4* g = (const uint4*)(WT + ((size_t)hd * F + ft * 64 + r) * F) + q * 4;
    uint4* lp = (uint4*)(As + r * LK) + q * 4;
    lp[0] = g[0]; lp[1] = g[1]; lp[2] = g[2]; lp[3] = g[3];
  }
  {
    int r = tid >> 2, q = tid & 3;
    const uint4* g = (const uint4*)(hb + ((size_t)(b * N + n0 + r)) * F) + q * 4;
    uint4* lp = (uint4*)(Bs + r * LK) + q * 4;
    lp[0] = g[0]; lp[1] = g[1]; lp[2] = g[2]; lp[3] = g[3];
  }
  __syncthreads();
  int arow = lane & 15, koff = (lane >> 4) * 8;
  f32x4 acc[4] = {};
#pragma unroll
  for (int ks = 0; ks < 4; ks++) {
    short8 bb = *(const short8*)(Bs + (w * 16 + arow) * LK + ks * 32 + koff);
#pragma unroll
    for (int rt = 0; rt < 4; rt++) {
      short8 a = *(const short8*)(As + (rt * 16 + arow) * LK + ks * 32 + koff);
      acc[rt] = mfma16(a, bb, acc[rt]);
    }
  }
  __syncthreads();
  int crow0 = (lane >> 4) * 4;
  {
    int nc = w * 16 + arow;
#pragma unroll
    for (int rt = 0; rt < 4; rt++)
#pragma unroll
      for (int r = 0; r < 4; r++)
        As[(rt * 16 + crow0 + r) * 72 + nc] = f2bf(acc[rt][r]);
  }
  __syncthreads();
  {
    short* outp = hhT + (size_t)bh * F * N + (size_t)(ft * 64) * N + n0;
    int r2 = tid >> 3, e = tid & 7;
#pragma unroll
    for (int rr = 0; rr < 2; rr++) {
      int r = rr * 32 + r2;
      uint4 pv = *(const uint4*)(As + r * 72 + e * 8);
      *(uint4*)(outp + (size_t)r * N + e * 8) = pv;
    }
  }
  const float* ah = ah_base + (size_t)hd * 2 * F;
  float pa1 = 0.f, pa2 = 0.f;
#pragma unroll
  for (int rt = 0; rt < 4; rt++) {
    int fo = ft * 64 + rt * 16 + crow0;
#pragma unroll
    for (int r = 0; r < 4; r++) {
      pa1 = fmaf(ah[fo + r], acc[rt][r], pa1);
      pa2 = fmaf(ah[F + fo + r], acc[rt][r], pa2);
    }
  }
  pa1 += __shfl_xor(pa1, 16); pa1 += __shfl_xor(pa1, 32);
  pa2 += __shfl_xor(pa2, 16); pa2 += __shfl_xor(pa2, 32);
  if (lane < 16) {
    int n = n0 + w * 16 + lane;
    atomicAdd(&s1[(size_t)bh * N + n], pa1);
    atomicAdd(&s2[(size_t)bh * N + n], pa2);
  }
}

// ========= fused attention, 8 heads — block-max softmax, ELU epilogue =====
// grid 1024 flat: b=bid&7, hd=(bid>>3)&7, nt=bid>>6. 32-row Q-tiles,
// 64-col V chunks. Row max bound = LR(s1[r] + max_all(s2)) — shift-invariant.
__global__ __launch_bounds__(256) void k_attn_heads7(
    const short* __restrict__ VT, const float* __restrict__ s1g,
    const float* __restrict__ s2g, const unsigned long long* __restrict__ amask,
    short* __restrict__ multi) {
  int bid = blockIdx.x;
  int b = bid & 7, hd = (bid >> 3) & 7, nt = bid >> 6;
  int bh = b * 8 + hd;
  int n0 = nt * 32;
  constexpr int LVK = 72;
  __shared__ short Vs[128 * LVK];
  __shared__ short Pf[4 * 64 * 8];
  __shared__ float s2all[512];
  __shared__ float s1r[32], linv[32];
  __shared__ float red[32][8];

  int tid = threadIdx.x, lane = tid & 63, w = tid >> 6;
  s2all[tid] = s2g[(size_t)bh * N + tid];
  s2all[tid + 256] = s2g[(size_t)bh * N + tid + 256];
  if (tid < 32) s1r[tid] = s1g[(size_t)bh * N + n0 + tid];
  __syncthreads();
  // block-wide unmasked max of s2 (12 ops vs 300-op masked prepass)
  float mx = fmaxf(s2all[tid], s2all[tid + 256]);
#pragma unroll
  for (int off = 32; off > 0; off >>= 1) mx = fmaxf(mx, __shfl_xor(mx, off));
  if (lane == 0) red[0][w] = mx;
  __syncthreads();
  float gmax = fmaxf(fmaxf(red[0][0], red[0][1]), fmaxf(red[0][2], red[0][3]));

  int prow = ((w >> 1) << 4) | (lane & 15);
  int pcol = ((w & 1) << 5) + ((lane >> 4) << 3);
  int pg = ((w & 1) << 2) | (lane >> 4);
  const unsigned long long* mp = amask + ((size_t)(b * N + n0 + prow)) * 8;
  float s1v = s1r[prow];
  float xm = s1v + gmax;
  float mr = fmaxf(xm, ALPHA_LR * xm);  // per-row upper bound, loop-constant
  float lp = 0.f;
  int arow = lane & 15, koff = (lane >> 4) * 8;
  f32x4 acc[2][2] = {};
  const short* Vg = VT + (size_t)bh * F * N;
  int fr = tid >> 1, hf = tid & 1;
  for (int mc = 0; mc < 8; mc++) {
    int m0 = mc * 64;
    __syncthreads();  // A: prior MFMA done with Vs/Pf
    {                 // stage V^T chunk: 128 f x 64 m
      const uint4* g4 = (const uint4*)(Vg + (size_t)fr * N + m0 + hf * 32);
      uint4* l4 = (uint4*)(Vs + fr * LVK + hf * 32);
      l4[0] = g4[0]; l4[1] = g4[1]; l4[2] = g4[2]; l4[3] = g4[3];
    }
    {  // P in A-fragment order
      unsigned bits = (unsigned)((mp[mc] >> pcol) & 0xffull);
      short8 pk;
#pragma unroll
      for (int j = 0; j < 8; j++) {
        float xv = s1v + s2all[m0 + pcol + j];
        xv = fmaxf(xv, ALPHA_LR * xv);  // LeakyReLU
        float p = __expf(xv - mr);
        p = ((bits >> j) & 1u) ? p : 0.f;
        lp += p;
        pk[j] = f2bf(p);
      }
      *(short8*)(Pf + (w * 64 + lane) * 8) = pk;
    }
    __syncthreads();  // B
#pragma unroll
    for (int ks = 0; ks < 2; ks++) {
      short8 a0 = *(const short8*)(Pf + ((0 * 2 + ks) * 64 + lane) * 8);
      short8 a1 = *(const short8*)(Pf + ((1 * 2 + ks) * 64 + lane) * 8);
#pragma unroll
      for (int cj = 0; cj < 2; cj++) {
        short8 bb = *(const short8*)(Vs + ((w * 2 + cj) * 16 + arow) * LVK +
                                     ks * 32 + koff);
        acc[0][cj] = mfma16(a0, bb, acc[0][cj]);
        acc[1][cj] = mfma16(a1, bb, acc[1][cj]);
      }
    }
  }
  __syncthreads();
  red[prow][pg] = lp;
  __syncthreads();
  if (tid < 32) {
    float ls = 0.f;
#pragma unroll
    for (int k = 0; k < 8; k++) ls += red[tid][k];
    linv[tid] = 1.f / ls;
  }
  __syncthreads();
  // packed-store epilogue via Vs reuse
  int crow0 = (lane >> 4) * 4;
#pragma unroll
  for (int rt = 0; rt < 2; rt++)
#pragma unroll
    for (int cj = 0; cj < 2; cj++) {
      int fcol = (w * 2 + cj) * 16 + arow;
#pragma unroll
      for (int rr = 0; rr < 4; rr++) {
        int nrow = rt * 16 + crow0 + rr;
        float v = acc[rt][cj][rr] * linv[nrow];
        v = v > 0.f ? v : __expf(v) - 1.f;  // ELU
        Vs[nrow * 136 + fcol] = f2bf(v);
      }
    }
  __syncthreads();
  {
    int r2 = tid >> 4, e = tid & 15;
#pragma unroll
    for (int rr = 0; rr < 2; rr++) {
      int r = rr * 16 + r2;
      uint4 pv = *(const uint4*)(Vs + r * 136 + e * 8);
      *(uint4*)(multi + ((size_t)(b * N + n0 + r)) * (H * F) + hd * F + e * 8) =
          pv;
    }
  }
}

// ========= out projection: hsT[b][f_out][n] = WoT . multi^T, + s1/s2 ======
// grid 256 flat (R11-exact, packed-store epilogue)
__global__ __launch_bounds__(256) void k_proj_out_mfma(
    const short* __restrict__ WoT, const short* __restrict__ multi,
    const float* __restrict__ ao, short* __restrict__ hsT,
    float* __restrict__ s1, float* __restrict__ s2) {
  int bid = blockIdx.x;
  int b = bid & 7, ft = (bid >> 3) & 3, nt = bid >> 5;
  constexpr int LK = 136;
  __shared__ short As[32 * LK];
  __shared__ short Bs[64 * LK];
  int tid = threadIdx.x, lane = tid & 63, w = tid >> 6;
  int arow = lane & 15, koff = (lane >> 4) * 8;
  const int KT = H * F;  // 1024
  f32x4 acc[2] = {};
  for (int k0 = 0; k0 < KT; k0 += 128) {
    __syncthreads();
    {
      int r = tid >> 3, e = tid & 7;
      const uint4* gp = (const uint4*)(WoT + (size_t)(ft * 32 + r) * KT + k0) + e * 2;
      uint4* lp = (uint4*)(As + r * LK) + e * 2;
      lp[0] = gp[0]; lp[1] = gp[1];
    }
    {
      int r = tid >> 2, q = tid & 3;
      const uint4* gp =
          (const uint4*)(multi + (size_t)(b * N + nt * 64 + r) * KT + k0) + q * 4;
      uint4* lp = (uint4*)(Bs + r * LK) + q * 4;
      lp[0] = gp[0]; lp[1] = gp[1]; lp[2] = gp[2]; lp[3] = gp[3];
    }
    __syncthreads();
#pragma unroll
    for (int ks = 0; ks < 4; ks++) {
      short8 b0 = *(const short8*)(Bs + (w * 16 + arow) * LK + ks * 32 + koff);
      short8 a0 = *(const short8*)(As + arow * LK + ks * 32 + koff);
      short8 a1 = *(const short8*)(As + (16 + arow) * LK + ks * 32 + koff);
      acc[0] = mfma16(a0, b0, acc[0]);
      acc[1] = mfma16(a1, b0, acc[1]);
    }
  }
  __syncthreads();
  int crow0 = (lane >> 4) * 4;
#pragma unroll
  for (int rt = 0; rt < 2; rt++)
#pragma unroll
    for (int r = 0; r < 4; r++)
      As[(rt * 16 + crow0 + r) * 72 + w * 16 + arow] = f2bf(acc[rt][r]);
  __syncthreads();
  {
    short* op = hsT + (size_t)b * F * N + (size_t)(ft * 32) * N + nt * 64;
    int r = tid >> 3, e = tid & 7;
    uint4 pv = *(const uint4*)(As + r * 72 + e * 8);
    *(uint4*)(op + (size_t)r * N + e * 8) = pv;
  }
  float pa1 = 0.f, pa2 = 0.f;
#pragma unroll
  for (int rt = 0; rt < 2; rt++) {
    int fo = ft * 32 + rt * 16 + crow0;
#pragma unroll
    for (int r = 0; r < 4; r++) {
      pa1 = fmaf(ao[fo + r], acc[rt][r], pa1);
      pa2 = fmaf(ao[F + fo + r], acc[rt][r], pa2);
    }
  }
  pa1 += __shfl_xor(pa1, 16); pa1 += __shfl_xor(pa1, 32);
  pa2 += __shfl_xor(pa2, 16); pa2 += __shfl_xor(pa2, 32);
  if (lane < 16) {
    int n = nt * 64 + w * 16 + lane;
    atomicAdd(&s1[(size_t)b * N + n], pa1);
    atomicAdd(&s2[(size_t)b * N + n], pa2);
  }
}

// ========= single-head attention + residual + LayerNorm — block-max =======
// grid 256 flat: b = bid&7, nt = bid>>3.
template <int LAST>
__global__ __launch_bounds__(256) void k_attn_single7(
    const short* __restrict__ VT, const float* __restrict__ s1g,
    const float* __restrict__ s2g, const unsigned long long* __restrict__ amask,
    const float* __restrict__ resid, const float* __restrict__ lng,
    const float* __restrict__ lnb, float* __restrict__ hout,
    short* __restrict__ hbout, float* __restrict__ dout) {
  int bid = blockIdx.x;
  int b = bid & 7, nt = bid >> 3;
  int n0 = nt * 16;
  constexpr int LVK = 136;
  __shared__ short Vs[128 * LVK];
  __shared__ short Pf[4 * 64 * 8];
  __shared__ float s2all[512];
  __shared__ float Ot[16][132];
  __shared__ float redS[16][16], redQ[16][16];
  __shared__ float s1r[16], linv[16], muA[16], rsA[16];

  int tid = threadIdx.x, lane = tid & 63, w = tid >> 6;
  s2all[tid] = s2g[(size_t)b * N + tid];
  s2all[tid + 256] = s2g[(size_t)b * N + tid + 256];
  if (tid < 16) s1r[tid] = s1g[(size_t)b * N + n0 + tid];
  __syncthreads();
  // block-wide unmasked max of s2
  float mx = fmaxf(s2all[tid], s2all[tid + 256]);
#pragma unroll
  for (int off = 32; off > 0; off >>= 1) mx = fmaxf(mx, __shfl_xor(mx, off));
  if (lane == 0) redS[0][w] = mx;
  __syncthreads();
  float gmax =
      fmaxf(fmaxf(redS[0][0], redS[0][1]), fmaxf(redS[0][2], redS[0][3]));

  float lp = 0.f;
  int arow = lane & 15, koff = (lane >> 4) * 8;
  int pr = tid & 15, pq = (tid >> 4) & 3;
  float s1v = s1r[pr];
  float xm0 = s1v + gmax;
  float mr = fmaxf(xm0, ALPHA_LR * xm0);
  f32x4 acc[2] = {};
  const short* Vg = VT + (size_t)b * F * N;
  const unsigned long long* mp = amask + ((size_t)(b * N + n0 + pr)) * 8;
  for (int mc = 0; mc < 4; mc++) {
    int m0 = mc * 128;
    __syncthreads();
    {
      int fr = tid >> 1, hf = tid & 1;
      const uint4* g4 = (const uint4*)(Vg + (size_t)fr * N + m0 + hf * 64);
      uint4* l4 = (uint4*)(Vs + fr * LVK + hf * 64);
#pragma unroll
      for (int k = 0; k < 8; k++) l4[k] = g4[k];
    }
    {
      unsigned bits = (unsigned)(mp[mc * 2 + (w >> 1)] >> ((w & 1) * 32));
      short8 pk;
#pragma unroll
      for (int j = 0; j < 8; j++) {
        float xv = s1v + s2all[m0 + w * 32 + pq * 8 + j];
        xv = fmaxf(xv, ALPHA_LR * xv);
        float p = __expf(xv - mr);
        p = ((bits >> (pq * 8 + j)) & 1u) ? p : 0.f;
        lp += p;
        pk[j] = f2bf(p);
      }
      *(short8*)(Pf + (w * 64 + ((pq << 4) | pr)) * 8) = pk;
    }
    __syncthreads();
#pragma unroll
    for (int ks = 0; ks < 4; ks++) {
      short8 a = *(const short8*)(Pf + (ks * 64 + lane) * 8);
#pragma unroll
      for (int cj = 0; cj < 2; cj++) {
        short8 bb = *(const short8*)(Vs + ((w * 2 + cj) * 16 + arow) * LVK +
                                     ks * 32 + koff);
        acc[cj] = mfma16(a, bb, acc[cj]);
      }
    }
  }
  __syncthreads();
  redS[pr][tid >> 4] = lp;
  __syncthreads();
  if (tid < 16) {
    float l = 0.f;
#pragma unroll
    for (int k = 0; k < 16; k++) l += redS[tid][k];
    linv[tid] = 1.f / l;
  }
  __syncthreads();
  int crow0 = (lane >> 4) * 4;
#pragma unroll
  for (int cj = 0; cj < 2; cj++) {
    int fcol = (w * 2 + cj) * 16 + arow;
#pragma unroll
    for (int rr = 0; rr < 4; rr++) {
      int row = crow0 + rr;
      Ot[row][fcol] = acc[cj][rr] * linv[row];
    }
  }
  __syncthreads();
  int r2 = tid >> 4, f8 = (tid & 15) * 8;
  size_t gbase = ((size_t)(b * N + n0 + r2)) * F + f8;
  float v[8];
  float s = 0.f, sq = 0.f;
#pragma unroll
  for (int j = 0; j < 8; j++) {
    float t = Ot[r2][f8 + j] + resid[gbase + j];
    v[j] = t;
    s += t;
    sq = fmaf(t, t, sq);
  }
  redS[r2][tid & 15] = s;
  redQ[r2][tid & 15] = sq;
  __syncthreads();
  if (tid < 16) {
    float ss = 0.f, qq = 0.f;
#pragma unroll
    for (int k = 0; k < 16; k++) { ss += redS[tid][k]; qq += redQ[tid][k]; }
    float mu = ss * (1.f / F);
    muA[tid] = mu;
    rsA[tid] = rsqrtf(qq * (1.f / F) - mu * mu + EPS_LN);
  }
  __syncthreads();
  float mu = muA[r2], rs = rsA[r2];
#pragma unroll
  for (int j = 0; j < 8; j++) {
    float y = (v[j] - mu) * rs * lng[f8 + j] + lnb[f8 + j];
    if (LAST) {
      dout[gbase + j] = y;
    } else {
      y = fmaxf(y, 0.f);
      hout[gbase + j] = y;
      hbout[gbase + j] = f2bf(y);
    }
  }
}

extern "C" void kernel_launch(void* const* d_in, const int* in_sizes, int n_in,
                              void* d_out, int out_size, void* d_ws,
                              size_t ws_size, hipStream_t stream) {
  const float* x = (const float*)d_in[0];
  const int* adj = (const int*)d_in[1];
  const float* Wp = (const float*)d_in[2];
  const float* bp = (const float*)d_in[3];
  const float* W_heads = (const float*)d_in[4];
  const float* a_heads = (const float*)d_in[5];
  const float* W_out = (const float*)d_in[6];
  const float* a_out = (const float*)d_in[7];
  const float* ln_g = (const float*)d_in[8];
  const float* ln_b = (const float*)d_in[9];

  char* p = (char*)d_ws;
  auto alloc = [&](size_t bytes) {
    char* r = p;
    p += (bytes + 255) & ~(size_t)255;
    return r;
  };
  float* sA = (float*)alloc((size_t)2 * 73728 * 4);
  short* WTh = (short*)alloc((size_t)2 * H * F * F * 2);
  short* WoT = (short*)alloc((size_t)2 * H * F * F * 2);
  unsigned long long* amask = (unsigned long long*)alloc((size_t)BN * 8 * 8);
  float* h = (float*)alloc((size_t)BN * F * 4);
  short* hb = (short*)alloc((size_t)BN * F * 2);
  short* hhT = (short*)alloc((size_t)B * H * F * N * 2);
  short* multi = (short*)alloc((size_t)BN * H * F * 2);
  short* hsT = (short*)alloc((size_t)B * F * N * 2);

  g_setup<<<512, 256, 0, stream>>>(x, adj, Wp, bp, W_heads, W_out, h, hb,
                                   amask, WTh, WoT, sA);
  for (int l = 0; l < 2; l++) {
    float* s1h = sA + (size_t)l * 73728;
    float* s2h = s1h + 32768;
    float* s1o = s2h + 32768;
    float* s2o = s1o + 4096;
    k_proj_heads_mfma2<<<dim3(1024), 256, 0, stream>>>(
        WTh + (size_t)l * H * F * F, hb, a_heads + (size_t)l * H * 2 * F, hhT,
        s1h, s2h);
    k_attn_heads7<<<dim3(1024), 256, 0, stream>>>(hhT, s1h, s2h, amask, multi);
    k_proj_out_mfma<<<dim3(256), 256, 0, stream>>>(
        WoT + (size_t)l * F * H * F, multi, a_out + (size_t)l * 2 * F, hsT, s1o,
        s2o);
    if (l == 0)
      k_attn_single7<0><<<dim3(256), 256, 0, stream>>>(
          hsT, s1o, s2o, amask, h, ln_g, ln_b, h, hb, nullptr);
    else
      k_attn_single7<1><<<dim3(256), 256, 0, stream>>>(
          hsT, s1o, s2o, amask, h, ln_g + F, ln_b + F, nullptr, nullptr,
          (float*)d_out);
  }
}